// Round 1
// baseline (1955.570 us; speedup 1.0000x reference)
//
#include <hip/hip_runtime.h>
#include <cstddef>

#define BB 8
#define NN 1024
#define KK 20
#define CCAT 169

// ---------------- squared norms: xx[b][n] = sum_f cur^2 ----------------
__global__ void xx_kernel(const float* __restrict__ src, int bs, int D,
                          float* __restrict__ xx) {
  int t = blockIdx.x * 256 + threadIdx.x;
  if (t >= BB * NN) return;
  int n = t & (NN - 1);
  int b = t >> 10;
  const float* p = src + (size_t)b * bs + n;
  float s = 0.f;
  int F = 3 * D;
  for (int f = 0; f < F; ++f) {
    float v = p[(size_t)f * NN];
    s += v * v;
  }
  xx[t] = s;
}

// ---------------- neg dist: dist[b][n][m] = 2*inner - xx[n] - xx[m] ----------------
__global__ void dist_kernel(const float* __restrict__ src, int bs, int D,
                            const float* __restrict__ xx,
                            float* __restrict__ dist) {
  // grid: x = 4*NN (4 m-quarters per n), y = B
  int m = (blockIdx.x & 3) * 256 + threadIdx.x;
  int n = blockIdx.x >> 2;
  int b = blockIdx.y;
  const float* p = src + (size_t)b * bs;
  float acc = 0.f;
  int F = 3 * D;
  for (int f = 0; f < F; ++f) {
    const float* row = p + (size_t)f * NN;
    acc += row[n] * row[m];
  }
  dist[(((size_t)b * NN + n) << 10) + m] =
      2.f * acc - xx[b * NN + n] - xx[b * NN + m];
}

// ---------------- top-k (k=20) per row, one wave per row ----------------
__global__ void topk_kernel(const float* __restrict__ dist,
                            int* __restrict__ idx_out) {
  int wave = threadIdx.x >> 6;
  int lane = threadIdx.x & 63;
  int row = blockIdx.x * 4 + wave;  // b*NN + n
  const float* d = dist + ((size_t)row << 10);
  float v[16];
  int ix[16];
#pragma unroll
  for (int s = 0; s < 16; ++s) {
    int m = lane + s * 64;
    v[s] = d[m];
    ix[s] = m;
  }
  int* out = idx_out + row * KK;
  for (int r = 0; r < KK; ++r) {
    float bv = -__builtin_inff();
    int bi = NN;
#pragma unroll
    for (int s = 0; s < 16; ++s) {
      if (v[s] > bv || (v[s] == bv && ix[s] < bi)) { bv = v[s]; bi = ix[s]; }
    }
    for (int off = 32; off > 0; off >>= 1) {
      float ov = __shfl_xor(bv, off, 64);
      int oi = __shfl_xor(bi, off, 64);
      if (ov > bv || (ov == bv && oi < bi)) { bv = ov; bi = oi; }
    }
    if (lane == 0) out[r] = bi;
#pragma unroll
    for (int s = 0; s < 16; ++s)
      if (ix[s] == bi) v[s] = -__builtin_inff();
  }
}

// ---------------- transforms: Uf/Vf/Ud/Vd [b][o][c][n] ----------------
// Uf = Wf[:, :D] @ cur   (neighbor part)
// Vf = (Wf[:, D:] - Wf[:, :D]) @ cur   (center part)
__global__ void transform_kernel(const float* __restrict__ src, int bs, int D,
                                 int Co, const float* __restrict__ Wf,
                                 const float* __restrict__ Wd,
                                 float* __restrict__ Uf, float* __restrict__ Vf,
                                 float* __restrict__ Ud, float* __restrict__ Vd) {
  int t = blockIdx.x * 256 + threadIdx.x;
  int total = BB * Co * 3 * NN;
  if (t >= total) return;
  int n = t & (NN - 1);
  int c = (t >> 10) % 3;
  int o = (t / (3 * NN)) % Co;
  int b = t / (3 * NN * Co);
  const float* p = src + (size_t)b * bs + (size_t)c * NN + n;
  const float* wf = Wf + o * 2 * D;
  const float* wd = Wd + o * 2 * D;
  float uf = 0.f, vf = 0.f, ud = 0.f, vd = 0.f;
  for (int i = 0; i < D; ++i) {
    float s = p[(size_t)i * 3 * NN];
    float af = wf[i], bf = wf[D + i] - af;
    float ad = wd[i], bd = wd[D + i] - ad;
    uf += af * s;
    vf += bf * s;
    ud += ad * s;
    vd += bd * s;
  }
  // t == ((b*Co + o)*3 + c)*NN + n
  Uf[t] = uf;
  Vf[t] = vf;
  Ud[t] = ud;
  Vd[t] = vd;
}

// ---------------- edge combine + mean over k -> xcat slice ----------------
__global__ void edge_kernel(const int* __restrict__ idx,
                            const float* __restrict__ Uf,
                            const float* __restrict__ Vf,
                            const float* __restrict__ Ud,
                            const float* __restrict__ Vd, int Co, int ooff,
                            float* __restrict__ xcat) {
  int t = blockIdx.x * 256 + threadIdx.x;
  int total = BB * Co * NN;
  if (t >= total) return;
  int n = t & (NN - 1);
  int o = (t >> 10) % Co;
  int b = t / (NN * Co);
  size_t base = (size_t)(b * Co + o) * 3 * NN;
  float vf0 = Vf[base + n], vf1 = Vf[base + NN + n], vf2 = Vf[base + 2 * NN + n];
  float vd0 = Vd[base + n], vd1 = Vd[base + NN + n], vd2 = Vd[base + 2 * NN + n];
  const int* ip = idx + (b * NN + n) * KK;
  float a0 = 0.f, a1 = 0.f, a2 = 0.f;
#pragma unroll 4
  for (int j = 0; j < KK; ++j) {
    int nb = ip[j];
    float pf0 = Uf[base + nb] + vf0;
    float pf1 = Uf[base + NN + nb] + vf1;
    float pf2 = Uf[base + 2 * NN + nb] + vf2;
    float pd0 = Ud[base + nb] + vd0;
    float pd1 = Ud[base + NN + nb] + vd1;
    float pd2 = Ud[base + 2 * NN + nb] + vd2;
    float dot = pf0 * pd0 + pf1 * pd1 + pf2 * pd2;
    float dsq = pd0 * pd0 + pd1 * pd1 + pd2 * pd2;
    // 0.2*p + 0.8*(dot>=0 ? p : p - dot/(dsq+eps)*d) = p - 0.8*min(dot,0)/(dsq+eps)*d
    float g = (dot >= 0.f) ? 0.f : 0.8f * dot / (dsq + 1e-6f);
    a0 += pf0 - g * pd0;
    a1 += pf1 - g * pd1;
    a2 += pf2 - g * pd2;
  }
  size_t ob = (size_t)b * CCAT * 3 * NN + (size_t)(ooff + o) * 3 * NN + n;
  const float inv_k = 1.f / KK;
  xcat[ob] = a0 * inv_k;
  xcat[ob + NN] = a1 * inv_k;
  xcat[ob + 2 * NN] = a2 * inv_k;
}

// ---------------- final layer d-vector (Cd = 1) ----------------
__global__ void dvec_kernel(const float* __restrict__ xcat,
                            const float* __restrict__ Wd4,
                            float* __restrict__ dbuf) {
  int t = blockIdx.x * 256 + threadIdx.x;  // B*3*N
  if (t >= BB * 3 * NN) return;
  int n = t & (NN - 1);
  int c = (t >> 10) % 3;
  int b = t / (3 * NN);
  const float* p = xcat + (size_t)b * CCAT * 3 * NN + (size_t)c * NN + n;
  float s = 0.f;
  for (int i = 0; i < CCAT; ++i) s += Wd4[i] * p[(size_t)i * 3 * NN];
  dbuf[t] = s;
}

// ---------------- final: GEMV + VN-leakyrelu + mean over N ----------------
__global__ void final_kernel(const float* __restrict__ xcat,
                             const float* __restrict__ Wf4,
                             const float* __restrict__ dbuf,
                             float* __restrict__ out) {
  int o = blockIdx.x;  // 0..340
  int b = blockIdx.y;
  int tid = threadIdx.x;
  __shared__ float wsm[CCAT];
  for (int i = tid; i < CCAT; i += 256) wsm[i] = Wf4[o * CCAT + i];
  __syncthreads();
  float s0 = 0.f, s1 = 0.f, s2 = 0.f;
  for (int n = tid; n < NN; n += 256) {
    const float* p = xcat + (size_t)b * CCAT * 3 * NN + n;
    float p0 = 0.f, p1 = 0.f, p2 = 0.f;
    for (int i = 0; i < CCAT; ++i) {
      float w = wsm[i];
      const float* q = p + (size_t)i * 3 * NN;
      p0 += w * q[0];
      p1 += w * q[NN];
      p2 += w * q[2 * NN];
    }
    float d0 = dbuf[(b * 3 + 0) * NN + n];
    float d1 = dbuf[(b * 3 + 1) * NN + n];
    float d2 = dbuf[(b * 3 + 2) * NN + n];
    float dot = p0 * d0 + p1 * d1 + p2 * d2;
    float dsq = d0 * d0 + d1 * d1 + d2 * d2;
    float g = (dot >= 0.f) ? 0.f : 0.8f * dot / (dsq + 1e-6f);
    s0 += p0 - g * d0;
    s1 += p1 - g * d1;
    s2 += p2 - g * d2;
  }
  __shared__ float r0[256], r1[256], r2[256];
  r0[tid] = s0;
  r1[tid] = s1;
  r2[tid] = s2;
  __syncthreads();
  for (int s = 128; s > 0; s >>= 1) {
    if (tid < s) {
      r0[tid] += r0[tid + s];
      r1[tid] += r1[tid + s];
      r2[tid] += r2[tid + s];
    }
    __syncthreads();
  }
  if (tid == 0) {
    float inv_n = 1.f / NN;
    out[(b * 341 + o) * 3 + 0] = r0[0] * inv_n;
    out[(b * 341 + o) * 3 + 1] = r1[0] * inv_n;
    out[(b * 341 + o) * 3 + 2] = r2[0] * inv_n;
  }
}

extern "C" void kernel_launch(void* const* d_in, const int* in_sizes, int n_in,
                              void* d_out, int out_size, void* d_ws,
                              size_t ws_size, hipStream_t stream) {
  (void)in_sizes; (void)n_in; (void)out_size; (void)ws_size;
  const float* x = (const float*)d_in[0];
  const float* Wf[5] = {(const float*)d_in[1], (const float*)d_in[3],
                        (const float*)d_in[5], (const float*)d_in[7],
                        (const float*)d_in[9]};
  const float* Wd[5] = {(const float*)d_in[2], (const float*)d_in[4],
                        (const float*)d_in[6], (const float*)d_in[8],
                        (const float*)d_in[10]};

  float* ws = (float*)d_ws;
  // dist matrix: B*N*N floats; U/V arrays alias it (dist dead after topk)
  float* dist = ws;
  const size_t UVSZ = (size_t)BB * 85 * 3 * NN;  // max Co = 85
  float* Uf = ws;
  float* Vf = Uf + UVSZ;
  float* Ud = Vf + UVSZ;
  float* Vd = Ud + UVSZ;
  size_t off = (size_t)BB * NN * NN;         // 8,388,608 floats
  int* idx = (int*)(ws + off);
  off += (size_t)BB * NN * KK;               // + 163,840
  float* xx = ws + off;
  off += (size_t)BB * NN;                    // + 8,192
  float* xcat = ws + off;
  off += (size_t)BB * CCAT * 3 * NN;         // + 4,153,344
  float* dbuf = ws + off;

  struct LayerCfg { int D, Co, inoff, ooff; };
  const LayerCfg L[4] = {
      {1, 21, 0, 0},    // input = x
      {21, 21, 0, 21},  // input = feats[0]
      {21, 42, 21, 42}, // input = feats[1]
      {42, 85, 42, 84}, // input = feats[2]
  };

  for (int l = 0; l < 4; ++l) {
    const float* src = (l == 0) ? x : (xcat + (size_t)L[l].inoff * 3 * NN);
    int bs = (l == 0) ? 3 * NN : CCAT * 3 * NN;
    int D = L[l].D, Co = L[l].Co;

    xx_kernel<<<(BB * NN) / 256, 256, 0, stream>>>(src, bs, D, xx);
    dist_kernel<<<dim3(4 * NN, BB), 256, 0, stream>>>(src, bs, D, xx, dist);
    topk_kernel<<<(BB * NN) / 4, 256, 0, stream>>>(dist, idx);
    int tt = BB * Co * 3 * NN;
    transform_kernel<<<(tt + 255) / 256, 256, 0, stream>>>(
        src, bs, D, Co, Wf[l], Wd[l], Uf, Vf, Ud, Vd);
    int te = BB * Co * NN;
    edge_kernel<<<(te + 255) / 256, 256, 0, stream>>>(idx, Uf, Vf, Ud, Vd, Co,
                                                      L[l].ooff, xcat);
  }

  dvec_kernel<<<(BB * 3 * NN) / 256, 256, 0, stream>>>(xcat, Wd[4], dbuf);
  final_kernel<<<dim3(341, BB), 256, 0, stream>>>(xcat, Wf[4], dbuf,
                                                  (float*)d_out);
}

// Round 2
// 1087.205 us; speedup vs baseline: 1.7987x; 1.7987x over previous
//
#include <hip/hip_runtime.h>
#include <cstddef>

#define BB 8
#define NN 1024
#define KK 20
#define CCAT 169

// ---------------- squared norms: xx[b][n] = sum_f cur^2 ----------------
__global__ void xx_kernel(const float* __restrict__ src, int bs, int D,
                          float* __restrict__ xx) {
  int t = blockIdx.x * 256 + threadIdx.x;
  if (t >= BB * NN) return;
  int n = t & (NN - 1);
  int b = t >> 10;
  const float* p = src + (size_t)b * bs + n;
  float s = 0.f;
  int F = 3 * D;
  for (int f = 0; f < F; ++f) {
    float v = p[(size_t)f * NN];
    s += v * v;
  }
  xx[t] = s;
}

// ---------------- neg dist, tiled GEMM-style ----------------
// dist[b][n][m] = 2*sum_f x[f][n]*x[f][m] - xx[n] - xx[m]
// 128x128 tile per 256-thread block, 8x8 micro-tile per thread,
// F staged through LDS in chunks of 8.
__global__ __launch_bounds__(256) void dist_tile_kernel(
    const float* __restrict__ src, int bs, int F,
    const float* __restrict__ xx, float* __restrict__ dist) {
  __shared__ float As[8][128];
  __shared__ float Bs[8][128];
  int b = blockIdx.z;
  int n0 = blockIdx.y * 128;
  int m0 = blockIdx.x * 128;
  int t = threadIdx.x;
  int tx = t & 15, ty = t >> 4;
  const float* p = src + (size_t)b * bs;

  float acc[8][8];
#pragma unroll
  for (int i = 0; i < 8; ++i)
#pragma unroll
    for (int j = 0; j < 8; ++j) acc[i][j] = 0.f;

  int fr = t >> 5;          // 0..7 : f row within chunk
  int cc = (t & 31) << 2;   // 0..124 : col group of 4
  for (int f0 = 0; f0 < F; f0 += 8) {
    int f = f0 + fr;
    float4 av = {0.f, 0.f, 0.f, 0.f}, bv = {0.f, 0.f, 0.f, 0.f};
    if (f < F) {
      av = *(const float4*)(p + (size_t)f * NN + n0 + cc);
      bv = *(const float4*)(p + (size_t)f * NN + m0 + cc);
    }
    __syncthreads();
    *(float4*)&As[fr][cc] = av;
    *(float4*)&Bs[fr][cc] = bv;
    __syncthreads();
#pragma unroll
    for (int f2 = 0; f2 < 8; ++f2) {
      float4 al = *(const float4*)&As[f2][ty << 2];
      float4 ah = *(const float4*)&As[f2][64 + (ty << 2)];
      float4 bl = *(const float4*)&Bs[f2][tx << 2];
      float4 bh = *(const float4*)&Bs[f2][64 + (tx << 2)];
      float a[8] = {al.x, al.y, al.z, al.w, ah.x, ah.y, ah.z, ah.w};
      float bb[8] = {bl.x, bl.y, bl.z, bl.w, bh.x, bh.y, bh.z, bh.w};
#pragma unroll
      for (int i = 0; i < 8; ++i)
#pragma unroll
        for (int j = 0; j < 8; ++j) acc[i][j] += a[i] * bb[j];
    }
  }

  const float* xb = xx + b * NN;
  float xn[8], xm[8];
#pragma unroll
  for (int i = 0; i < 4; ++i) {
    xn[i] = xb[n0 + (ty << 2) + i];
    xn[4 + i] = xb[n0 + 64 + (ty << 2) + i];
    xm[i] = xb[m0 + (tx << 2) + i];
    xm[4 + i] = xb[m0 + 64 + (tx << 2) + i];
  }
#pragma unroll
  for (int i = 0; i < 8; ++i) {
    int n = n0 + ((i < 4) ? ((ty << 2) + i) : (64 + (ty << 2) + i - 4));
    float* dr = dist + (((size_t)b * NN + n) << 10);
    float4 w0, w1;
    w0.x = 2.f * acc[i][0] - xn[i] - xm[0];
    w0.y = 2.f * acc[i][1] - xn[i] - xm[1];
    w0.z = 2.f * acc[i][2] - xn[i] - xm[2];
    w0.w = 2.f * acc[i][3] - xn[i] - xm[3];
    w1.x = 2.f * acc[i][4] - xn[i] - xm[4];
    w1.y = 2.f * acc[i][5] - xn[i] - xm[5];
    w1.z = 2.f * acc[i][6] - xn[i] - xm[6];
    w1.w = 2.f * acc[i][7] - xn[i] - xm[7];
    *(float4*)(dr + m0 + (tx << 2)) = w0;
    *(float4*)(dr + m0 + 64 + (tx << 2)) = w1;
  }
}

// ---------------- top-k (k=20) per row, one wave per row ----------------
__global__ void topk_kernel(const float* __restrict__ dist,
                            int* __restrict__ idx_out) {
  int wave = threadIdx.x >> 6;
  int lane = threadIdx.x & 63;
  int row = blockIdx.x * 4 + wave;  // b*NN + n
  const float* d = dist + ((size_t)row << 10);
  float v[16];
  int ix[16];
#pragma unroll
  for (int s = 0; s < 16; ++s) {
    int m = lane + s * 64;
    v[s] = d[m];
    ix[s] = m;
  }
  int* out = idx_out + row * KK;
  for (int r = 0; r < KK; ++r) {
    float bv = -__builtin_inff();
    int bi = NN;
#pragma unroll
    for (int s = 0; s < 16; ++s) {
      if (v[s] > bv || (v[s] == bv && ix[s] < bi)) { bv = v[s]; bi = ix[s]; }
    }
    for (int off = 32; off > 0; off >>= 1) {
      float ov = __shfl_xor(bv, off, 64);
      int oi = __shfl_xor(bi, off, 64);
      if (ov > bv || (ov == bv && oi < bi)) { bv = ov; bi = oi; }
    }
    if (lane == 0) out[r] = bi;
#pragma unroll
    for (int s = 0; s < 16; ++s)
      if (ix[s] == bi) v[s] = -__builtin_inff();
  }
}

// ---------------- transforms: Uf/Vf/Ud/Vd [b][o][c][n] ----------------
__global__ void transform_kernel(const float* __restrict__ src, int bs, int D,
                                 int Co, const float* __restrict__ Wf,
                                 const float* __restrict__ Wd,
                                 float* __restrict__ Uf, float* __restrict__ Vf,
                                 float* __restrict__ Ud, float* __restrict__ Vd) {
  int t = blockIdx.x * 256 + threadIdx.x;
  int total = BB * Co * 3 * NN;
  if (t >= total) return;
  int n = t & (NN - 1);
  int c = (t >> 10) % 3;
  int o = (t / (3 * NN)) % Co;
  int b = t / (3 * NN * Co);
  const float* p = src + (size_t)b * bs + (size_t)c * NN + n;
  const float* wf = Wf + o * 2 * D;
  const float* wd = Wd + o * 2 * D;
  float uf = 0.f, vf = 0.f, ud = 0.f, vd = 0.f;
  for (int i = 0; i < D; ++i) {
    float s = p[(size_t)i * 3 * NN];
    float af = wf[i], bf = wf[D + i] - af;
    float ad = wd[i], bd = wd[D + i] - ad;
    uf += af * s;
    vf += bf * s;
    ud += ad * s;
    vd += bd * s;
  }
  Uf[t] = uf;
  Vf[t] = vf;
  Ud[t] = ud;
  Vd[t] = vd;
}

// ---------------- edge combine + mean over k -> xcat slice ----------------
__global__ void edge_kernel(const int* __restrict__ idx,
                            const float* __restrict__ Uf,
                            const float* __restrict__ Vf,
                            const float* __restrict__ Ud,
                            const float* __restrict__ Vd, int Co, int ooff,
                            float* __restrict__ xcat) {
  int t = blockIdx.x * 256 + threadIdx.x;
  int total = BB * Co * NN;
  if (t >= total) return;
  int n = t & (NN - 1);
  int o = (t >> 10) % Co;
  int b = t / (NN * Co);
  size_t base = (size_t)(b * Co + o) * 3 * NN;
  float vf0 = Vf[base + n], vf1 = Vf[base + NN + n], vf2 = Vf[base + 2 * NN + n];
  float vd0 = Vd[base + n], vd1 = Vd[base + NN + n], vd2 = Vd[base + 2 * NN + n];
  const int* ip = idx + (b * NN + n) * KK;
  float a0 = 0.f, a1 = 0.f, a2 = 0.f;
#pragma unroll 4
  for (int j = 0; j < KK; ++j) {
    int nb = ip[j];
    float pf0 = Uf[base + nb] + vf0;
    float pf1 = Uf[base + NN + nb] + vf1;
    float pf2 = Uf[base + 2 * NN + nb] + vf2;
    float pd0 = Ud[base + nb] + vd0;
    float pd1 = Ud[base + NN + nb] + vd1;
    float pd2 = Ud[base + 2 * NN + nb] + vd2;
    float dot = pf0 * pd0 + pf1 * pd1 + pf2 * pd2;
    float dsq = pd0 * pd0 + pd1 * pd1 + pd2 * pd2;
    float g = (dot >= 0.f) ? 0.f : 0.8f * dot / (dsq + 1e-6f);
    a0 += pf0 - g * pd0;
    a1 += pf1 - g * pd1;
    a2 += pf2 - g * pd2;
  }
  size_t ob = (size_t)b * CCAT * 3 * NN + (size_t)(ooff + o) * 3 * NN + n;
  const float inv_k = 1.f / KK;
  xcat[ob] = a0 * inv_k;
  xcat[ob + NN] = a1 * inv_k;
  xcat[ob + 2 * NN] = a2 * inv_k;
}

// ---------------- final layer d-vector (Cd = 1) ----------------
__global__ void dvec_kernel(const float* __restrict__ xcat,
                            const float* __restrict__ Wd4,
                            float* __restrict__ dbuf) {
  int t = blockIdx.x * 256 + threadIdx.x;  // B*3*N
  if (t >= BB * 3 * NN) return;
  int n = t & (NN - 1);
  int c = (t >> 10) % 3;
  int b = t / (3 * NN);
  const float* p = xcat + (size_t)b * CCAT * 3 * NN + (size_t)c * NN + n;
  float s = 0.f;
  for (int i = 0; i < CCAT; ++i) s += Wd4[i] * p[(size_t)i * 3 * NN];
  dbuf[t] = s;
}

// ---------------- final: GEMV + VN-leakyrelu + mean over N ----------------
__global__ void final_kernel(const float* __restrict__ xcat,
                             const float* __restrict__ Wf4,
                             const float* __restrict__ dbuf,
                             float* __restrict__ out) {
  int o = blockIdx.x;  // 0..340
  int b = blockIdx.y;
  int tid = threadIdx.x;
  __shared__ float wsm[CCAT];
  for (int i = tid; i < CCAT; i += 256) wsm[i] = Wf4[o * CCAT + i];
  __syncthreads();
  float s0 = 0.f, s1 = 0.f, s2 = 0.f;
  for (int n = tid; n < NN; n += 256) {
    const float* p = xcat + (size_t)b * CCAT * 3 * NN + n;
    float p0 = 0.f, p1 = 0.f, p2 = 0.f;
    for (int i = 0; i < CCAT; ++i) {
      float w = wsm[i];
      const float* q = p + (size_t)i * 3 * NN;
      p0 += w * q[0];
      p1 += w * q[NN];
      p2 += w * q[2 * NN];
    }
    float d0 = dbuf[(b * 3 + 0) * NN + n];
    float d1 = dbuf[(b * 3 + 1) * NN + n];
    float d2 = dbuf[(b * 3 + 2) * NN + n];
    float dot = p0 * d0 + p1 * d1 + p2 * d2;
    float dsq = d0 * d0 + d1 * d1 + d2 * d2;
    float g = (dot >= 0.f) ? 0.f : 0.8f * dot / (dsq + 1e-6f);
    s0 += p0 - g * d0;
    s1 += p1 - g * d1;
    s2 += p2 - g * d2;
  }
  __shared__ float r0[256], r1[256], r2[256];
  r0[tid] = s0;
  r1[tid] = s1;
  r2[tid] = s2;
  __syncthreads();
  for (int s = 128; s > 0; s >>= 1) {
    if (tid < s) {
      r0[tid] += r0[tid + s];
      r1[tid] += r1[tid + s];
      r2[tid] += r2[tid + s];
    }
    __syncthreads();
  }
  if (tid == 0) {
    float inv_n = 1.f / NN;
    out[(b * 341 + o) * 3 + 0] = r0[0] * inv_n;
    out[(b * 341 + o) * 3 + 1] = r1[0] * inv_n;
    out[(b * 341 + o) * 3 + 2] = r2[0] * inv_n;
  }
}

extern "C" void kernel_launch(void* const* d_in, const int* in_sizes, int n_in,
                              void* d_out, int out_size, void* d_ws,
                              size_t ws_size, hipStream_t stream) {
  (void)in_sizes; (void)n_in; (void)out_size; (void)ws_size;
  const float* x = (const float*)d_in[0];
  const float* Wf[5] = {(const float*)d_in[1], (const float*)d_in[3],
                        (const float*)d_in[5], (const float*)d_in[7],
                        (const float*)d_in[9]};
  const float* Wd[5] = {(const float*)d_in[2], (const float*)d_in[4],
                        (const float*)d_in[6], (const float*)d_in[8],
                        (const float*)d_in[10]};

  float* ws = (float*)d_ws;
  float* dist = ws;
  const size_t UVSZ = (size_t)BB * 85 * 3 * NN;  // max Co = 85
  float* Uf = ws;
  float* Vf = Uf + UVSZ;
  float* Ud = Vf + UVSZ;
  float* Vd = Ud + UVSZ;
  size_t off = (size_t)BB * NN * NN;
  int* idx = (int*)(ws + off);
  off += (size_t)BB * NN * KK;
  float* xx = ws + off;
  off += (size_t)BB * NN;
  float* xcat = ws + off;
  off += (size_t)BB * CCAT * 3 * NN;
  float* dbuf = ws + off;

  struct LayerCfg { int D, Co, inoff, ooff; };
  const LayerCfg L[4] = {
      {1, 21, 0, 0},
      {21, 21, 0, 21},
      {21, 42, 21, 42},
      {42, 85, 42, 84},
  };

  for (int l = 0; l < 4; ++l) {
    const float* src = (l == 0) ? x : (xcat + (size_t)L[l].inoff * 3 * NN);
    int bs = (l == 0) ? 3 * NN : CCAT * 3 * NN;
    int D = L[l].D, Co = L[l].Co;

    xx_kernel<<<(BB * NN) / 256, 256, 0, stream>>>(src, bs, D, xx);
    dist_tile_kernel<<<dim3(8, 8, BB), 256, 0, stream>>>(src, bs, 3 * D, xx,
                                                         dist);
    topk_kernel<<<(BB * NN) / 4, 256, 0, stream>>>(dist, idx);
    int tt = BB * Co * 3 * NN;
    transform_kernel<<<(tt + 255) / 256, 256, 0, stream>>>(
        src, bs, D, Co, Wf[l], Wd[l], Uf, Vf, Ud, Vd);
    int te = BB * Co * NN;
    edge_kernel<<<(te + 255) / 256, 256, 0, stream>>>(idx, Uf, Vf, Ud, Vd, Co,
                                                      L[l].ooff, xcat);
  }

  dvec_kernel<<<(BB * 3 * NN) / 256, 256, 0, stream>>>(xcat, Wd[4], dbuf);
  final_kernel<<<dim3(341, BB), 256, 0, stream>>>(xcat, Wf[4], dbuf,
                                                  (float*)d_out);
}

// Round 4
// 971.424 us; speedup vs baseline: 2.0131x; 1.1192x over previous
//
#include <hip/hip_runtime.h>
#include <cstddef>

#define BB 8
#define NN 1024
#define KK 20
#define CCAT 169
#define NT 8  // n-tiles of 128 in final fused GEMM

// ---------------- squared norms: xx[b][n] = sum_f cur^2 ----------------
__global__ void xx_kernel(const float* __restrict__ src, int bs, int D,
                          float* __restrict__ xx) {
  int t = blockIdx.x * 256 + threadIdx.x;
  if (t >= BB * NN) return;
  int n = t & (NN - 1);
  int b = t >> 10;
  const float* p = src + (size_t)b * bs + n;
  float s = 0.f;
  int F = 3 * D;
  for (int f = 0; f < F; ++f) {
    float v = p[(size_t)f * NN];
    s += v * v;
  }
  xx[t] = s;
}

// ---------------- neg dist, tiled GEMM-style ----------------
__global__ __launch_bounds__(256) void dist_tile_kernel(
    const float* __restrict__ src, int bs, int F,
    const float* __restrict__ xx, float* __restrict__ dist) {
  __shared__ float As[8][128];
  __shared__ float Bs[8][128];
  int b = blockIdx.z;
  int n0 = blockIdx.y * 128;
  int m0 = blockIdx.x * 128;
  int t = threadIdx.x;
  int tx = t & 15, ty = t >> 4;
  const float* p = src + (size_t)b * bs;

  float acc[8][8];
#pragma unroll
  for (int i = 0; i < 8; ++i)
#pragma unroll
    for (int j = 0; j < 8; ++j) acc[i][j] = 0.f;

  int fr = t >> 5;
  int cc = (t & 31) << 2;
  for (int f0 = 0; f0 < F; f0 += 8) {
    int f = f0 + fr;
    float4 av = {0.f, 0.f, 0.f, 0.f}, bv = {0.f, 0.f, 0.f, 0.f};
    if (f < F) {
      av = *(const float4*)(p + (size_t)f * NN + n0 + cc);
      bv = *(const float4*)(p + (size_t)f * NN + m0 + cc);
    }
    __syncthreads();
    *(float4*)&As[fr][cc] = av;
    *(float4*)&Bs[fr][cc] = bv;
    __syncthreads();
#pragma unroll
    for (int f2 = 0; f2 < 8; ++f2) {
      float4 al = *(const float4*)&As[f2][ty << 2];
      float4 ah = *(const float4*)&As[f2][64 + (ty << 2)];
      float4 bl = *(const float4*)&Bs[f2][tx << 2];
      float4 bh = *(const float4*)&Bs[f2][64 + (tx << 2)];
      float a[8] = {al.x, al.y, al.z, al.w, ah.x, ah.y, ah.z, ah.w};
      float bb[8] = {bl.x, bl.y, bl.z, bl.w, bh.x, bh.y, bh.z, bh.w};
#pragma unroll
      for (int i = 0; i < 8; ++i)
#pragma unroll
        for (int j = 0; j < 8; ++j) acc[i][j] += a[i] * bb[j];
    }
  }

  const float* xb = xx + b * NN;
  float xn[8], xm[8];
#pragma unroll
  for (int i = 0; i < 4; ++i) {
    xn[i] = xb[n0 + (ty << 2) + i];
    xn[4 + i] = xb[n0 + 64 + (ty << 2) + i];
    xm[i] = xb[m0 + (tx << 2) + i];
    xm[4 + i] = xb[m0 + 64 + (tx << 2) + i];
  }
#pragma unroll
  for (int i = 0; i < 8; ++i) {
    int n = n0 + ((i < 4) ? ((ty << 2) + i) : (64 + (ty << 2) + i - 4));
    float* dr = dist + (((size_t)b * NN + n) << 10);
    float4 w0, w1;
    w0.x = 2.f * acc[i][0] - xn[i] - xm[0];
    w0.y = 2.f * acc[i][1] - xn[i] - xm[1];
    w0.z = 2.f * acc[i][2] - xn[i] - xm[2];
    w0.w = 2.f * acc[i][3] - xn[i] - xm[3];
    w1.x = 2.f * acc[i][4] - xn[i] - xm[4];
    w1.y = 2.f * acc[i][5] - xn[i] - xm[5];
    w1.z = 2.f * acc[i][6] - xn[i] - xm[6];
    w1.w = 2.f * acc[i][7] - xn[i] - xm[7];
    *(float4*)(dr + m0 + (tx << 2)) = w0;
    *(float4*)(dr + m0 + 64 + (tx << 2)) = w1;
  }
}

// ---------------- top-k (k=20) per row, one wave per row ----------------
__global__ void topk_kernel(const float* __restrict__ dist,
                            int* __restrict__ idx_out) {
  int wave = threadIdx.x >> 6;
  int lane = threadIdx.x & 63;
  int row = blockIdx.x * 4 + wave;
  const float* d = dist + ((size_t)row << 10);
  float v[16];
  int ix[16];
#pragma unroll
  for (int s = 0; s < 16; ++s) {
    int m = lane + s * 64;
    v[s] = d[m];
    ix[s] = m;
  }
  int* out = idx_out + row * KK;
  for (int r = 0; r < KK; ++r) {
    float bv = -__builtin_inff();
    int bi = NN;
#pragma unroll
    for (int s = 0; s < 16; ++s) {
      if (v[s] > bv || (v[s] == bv && ix[s] < bi)) { bv = v[s]; bi = ix[s]; }
    }
    for (int off = 32; off > 0; off >>= 1) {
      float ov = __shfl_xor(bv, off, 64);
      int oi = __shfl_xor(bi, off, 64);
      if (ov > bv || (ov == bv && oi < bi)) { bv = ov; bi = oi; }
    }
    if (lane == 0) out[r] = bi;
#pragma unroll
    for (int s = 0; s < 16; ++s)
      if (ix[s] == bi) v[s] = -__builtin_inff();
  }
}

// ---------------- transforms: Uf/Vf/Ud/Vd [b][o][c][n] ----------------
__global__ void transform_kernel(const float* __restrict__ src, int bs, int D,
                                 int Co, const float* __restrict__ Wf,
                                 const float* __restrict__ Wd,
                                 float* __restrict__ Uf, float* __restrict__ Vf,
                                 float* __restrict__ Ud, float* __restrict__ Vd) {
  int t = blockIdx.x * 256 + threadIdx.x;
  int total = BB * Co * 3 * NN;
  if (t >= total) return;
  int n = t & (NN - 1);
  int c = (t >> 10) % 3;
  int o = (t / (3 * NN)) % Co;
  int b = t / (3 * NN * Co);
  const float* p = src + (size_t)b * bs + (size_t)c * NN + n;
  const float* wf = Wf + o * 2 * D;
  const float* wd = Wd + o * 2 * D;
  float uf = 0.f, vf = 0.f, ud = 0.f, vd = 0.f;
  for (int i = 0; i < D; ++i) {
    float s = p[(size_t)i * 3 * NN];
    float af = wf[i], bf = wf[D + i] - af;
    float ad = wd[i], bd = wd[D + i] - ad;
    uf += af * s;
    vf += bf * s;
    ud += ad * s;
    vd += bd * s;
  }
  Uf[t] = uf;
  Vf[t] = vf;
  Ud[t] = ud;
  Vd[t] = vd;
}

// ---------------- edge combine + mean over k -> xcat slice ----------------
__global__ void edge_kernel(const int* __restrict__ idx,
                            const float* __restrict__ Uf,
                            const float* __restrict__ Vf,
                            const float* __restrict__ Ud,
                            const float* __restrict__ Vd, int Co, int ooff,
                            float* __restrict__ xcat) {
  int t = blockIdx.x * 256 + threadIdx.x;
  int total = BB * Co * NN;
  if (t >= total) return;
  int n = t & (NN - 1);
  int o = (t >> 10) % Co;
  int b = t / (NN * Co);
  size_t base = (size_t)(b * Co + o) * 3 * NN;
  float vf0 = Vf[base + n], vf1 = Vf[base + NN + n], vf2 = Vf[base + 2 * NN + n];
  float vd0 = Vd[base + n], vd1 = Vd[base + NN + n], vd2 = Vd[base + 2 * NN + n];
  const int* ip = idx + (b * NN + n) * KK;
  float a0 = 0.f, a1 = 0.f, a2 = 0.f;
#pragma unroll 4
  for (int j = 0; j < KK; ++j) {
    int nb = ip[j];
    float pf0 = Uf[base + nb] + vf0;
    float pf1 = Uf[base + NN + nb] + vf1;
    float pf2 = Uf[base + 2 * NN + nb] + vf2;
    float pd0 = Ud[base + nb] + vd0;
    float pd1 = Ud[base + NN + nb] + vd1;
    float pd2 = Ud[base + 2 * NN + nb] + vd2;
    float dot = pf0 * pd0 + pf1 * pd1 + pf2 * pd2;
    float dsq = pd0 * pd0 + pd1 * pd1 + pd2 * pd2;
    float g = (dot >= 0.f) ? 0.f : 0.8f * dot / (dsq + 1e-6f);
    a0 += pf0 - g * pd0;
    a1 += pf1 - g * pd1;
    a2 += pf2 - g * pd2;
  }
  size_t ob = (size_t)b * CCAT * 3 * NN + (size_t)(ooff + o) * 3 * NN + n;
  const float inv_k = 1.f / KK;
  xcat[ob] = a0 * inv_k;
  xcat[ob + NN] = a1 * inv_k;
  xcat[ob + 2 * NN] = a2 * inv_k;
}

// ---------------- final layer d-vector (Cd = 1) ----------------
__global__ void dvec_kernel(const float* __restrict__ xcat,
                            const float* __restrict__ Wd4,
                            float* __restrict__ dbuf) {
  int t = blockIdx.x * 256 + threadIdx.x;
  if (t >= BB * 3 * NN) return;
  int n = t & (NN - 1);
  int c = (t >> 10) % 3;
  int b = t / (3 * NN);
  const float* p = xcat + (size_t)b * CCAT * 3 * NN + (size_t)c * NN + n;
  float s = 0.f;
  for (int i = 0; i < CCAT; ++i) s += Wd4[i] * p[(size_t)i * 3 * NN];
  dbuf[t] = s;
}

// ---------------- fused final GEMM + VN-leakyrelu + partial n-sum ----------------
// Tile: 64 o x 128 n per block, all 3 c-planes; K=169 staged in chunks of 8.
// part[((b*341+o)*3+c)*NT + ntile] = sum over this n-tile.
__global__ __launch_bounds__(256) void final_fused_kernel(
    const float* __restrict__ xcat, const float* __restrict__ Wf4,
    const float* __restrict__ dbuf, float* __restrict__ part) {
  __shared__ float Ws[8][64];
  __shared__ float Xs[3][8][128];
  int b = blockIdx.z;
  int o0 = blockIdx.y * 64;
  int n0 = blockIdx.x * 128;
  int t = threadIdx.x;
  int tx = t & 15, ty = t >> 4;

  float acc[3][4][8];
#pragma unroll
  for (int c = 0; c < 3; ++c)
#pragma unroll
    for (int i = 0; i < 4; ++i)
#pragma unroll
      for (int j = 0; j < 8; ++j) acc[c][i][j] = 0.f;

  const float* xb = xcat + (size_t)b * CCAT * 3 * NN;
  int fr = t >> 5;
  int cc = (t & 31) << 2;
  for (int f0 = 0; f0 < CCAT; f0 += 8) {
    int f = f0 + fr;
    float4 xv[3];
#pragma unroll
    for (int c = 0; c < 3; ++c) {
      xv[c] = make_float4(0.f, 0.f, 0.f, 0.f);
      if (f < CCAT)
        xv[c] = *(const float4*)(xb + ((size_t)f * 3 + c) * NN + n0 + cc);
    }
    float wv[2];
#pragma unroll
    for (int q = 0; q < 2; ++q) {
      int e = t * 2 + q;
      int oo = e & 63, kk = e >> 6;
      int o = o0 + oo, ff = f0 + kk;
      wv[q] = (o < 341 && ff < CCAT) ? Wf4[o * CCAT + ff] : 0.f;
    }
    __syncthreads();
#pragma unroll
    for (int c = 0; c < 3; ++c) *(float4*)&Xs[c][fr][cc] = xv[c];
    {
      int e = t * 2;
      *(float2*)&Ws[e >> 6][e & 63] = make_float2(wv[0], wv[1]);
    }
    __syncthreads();
#pragma unroll
    for (int f2 = 0; f2 < 8; ++f2) {
      float4 w = *(const float4*)&Ws[f2][ty << 2];
      float wa[4] = {w.x, w.y, w.z, w.w};
#pragma unroll
      for (int c = 0; c < 3; ++c) {
        float4 xl = *(const float4*)&Xs[c][f2][tx << 2];
        float4 xh = *(const float4*)&Xs[c][f2][64 + (tx << 2)];
        float xa[8] = {xl.x, xl.y, xl.z, xl.w, xh.x, xh.y, xh.z, xh.w};
#pragma unroll
        for (int i = 0; i < 4; ++i)
#pragma unroll
          for (int j = 0; j < 8; ++j) acc[c][i][j] += wa[i] * xa[j];
      }
    }
  }

  // d values for my 8 n x 3 c
  const float* db = dbuf + b * 3 * NN;
  float da[3][8];
#pragma unroll
  for (int c = 0; c < 3; ++c) {
    float4 dl = *(const float4*)(db + c * NN + n0 + (tx << 2));
    float4 dh = *(const float4*)(db + c * NN + n0 + 64 + (tx << 2));
    da[c][0] = dl.x; da[c][1] = dl.y; da[c][2] = dl.z; da[c][3] = dl.w;
    da[c][4] = dh.x; da[c][5] = dh.y; da[c][6] = dh.z; da[c][7] = dh.w;
  }

  float s[3][4];
#pragma unroll
  for (int c = 0; c < 3; ++c)
#pragma unroll
    for (int i = 0; i < 4; ++i) s[c][i] = 0.f;
#pragma unroll
  for (int i = 0; i < 4; ++i) {
#pragma unroll
    for (int j = 0; j < 8; ++j) {
      float d0 = da[0][j], d1 = da[1][j], d2 = da[2][j];
      float p0 = acc[0][i][j], p1 = acc[1][i][j], p2 = acc[2][i][j];
      float dot = p0 * d0 + p1 * d1 + p2 * d2;
      float dsq = d0 * d0 + d1 * d1 + d2 * d2;
      float g = (dot >= 0.f) ? 0.f : 0.8f * dot / (dsq + 1e-6f);
      s[0][i] += p0 - g * d0;
      s[1][i] += p1 - g * d1;
      s[2][i] += p2 - g * d2;
    }
  }

  // reduce across tx (lane bits [3:0] within each wave)
#pragma unroll
  for (int off = 1; off < 16; off <<= 1) {
#pragma unroll
    for (int c = 0; c < 3; ++c)
#pragma unroll
      for (int i = 0; i < 4; ++i) s[c][i] += __shfl_xor(s[c][i], off, 64);
  }
  if (tx == 0) {
#pragma unroll
    for (int i = 0; i < 4; ++i) {
      int o = o0 + (ty << 2) + i;
      if (o < 341) {
#pragma unroll
        for (int c = 0; c < 3; ++c)
          part[(((size_t)b * 341 + o) * 3 + c) * NT + blockIdx.x] = s[c][i];
      }
    }
  }
}

__global__ void final_reduce_kernel(const float* __restrict__ part,
                                    float* __restrict__ out) {
  int t = blockIdx.x * 256 + threadIdx.x;
  if (t >= BB * 341 * 3) return;
  const float* p = part + (size_t)t * NT;
  float s = 0.f;
#pragma unroll
  for (int nt = 0; nt < NT; ++nt) s += p[nt];
  out[t] = s * (1.f / 1024.f);
}

extern "C" void kernel_launch(void* const* d_in, const int* in_sizes, int n_in,
                              void* d_out, int out_size, void* d_ws,
                              size_t ws_size, hipStream_t stream) {
  (void)in_sizes; (void)n_in; (void)out_size; (void)ws_size;
  const float* x = (const float*)d_in[0];
  const float* Wf[5] = {(const float*)d_in[1], (const float*)d_in[3],
                        (const float*)d_in[5], (const float*)d_in[7],
                        (const float*)d_in[9]};
  const float* Wd[5] = {(const float*)d_in[2], (const float*)d_in[4],
                        (const float*)d_in[6], (const float*)d_in[8],
                        (const float*)d_in[10]};

  float* ws = (float*)d_ws;
  float* dist = ws;
  const size_t UVSZ = (size_t)BB * 85 * 3 * NN;
  float* Uf = ws;
  float* Vf = Uf + UVSZ;
  float* Ud = Vf + UVSZ;
  float* Vd = Ud + UVSZ;
  float* part = ws;  // dist/UV region is dead by the time part is written
  size_t off = (size_t)BB * NN * NN;
  int* idx = (int*)(ws + off);
  off += (size_t)BB * NN * KK;
  float* xx = ws + off;
  off += (size_t)BB * NN;
  float* xcat = ws + off;
  off += (size_t)BB * CCAT * 3 * NN;
  float* dbuf = ws + off;

  struct LayerCfg { int D, Co, inoff, ooff; };
  const LayerCfg L[4] = {
      {1, 21, 0, 0},
      {21, 21, 0, 21},
      {21, 42, 21, 42},
      {42, 85, 42, 84},
  };

  for (int l = 0; l < 4; ++l) {
    const float* src = (l == 0) ? x : (xcat + (size_t)L[l].inoff * 3 * NN);
    int bs = (l == 0) ? 3 * NN : CCAT * 3 * NN;
    int D = L[l].D, Co = L[l].Co;

    xx_kernel<<<(BB * NN) / 256, 256, 0, stream>>>(src, bs, D, xx);
    dist_tile_kernel<<<dim3(8, 8, BB), 256, 0, stream>>>(src, bs, 3 * D, xx,
                                                         dist);
    topk_kernel<<<(BB * NN) / 4, 256, 0, stream>>>(dist, idx);
    int tt = BB * Co * 3 * NN;
    transform_kernel<<<(tt + 255) / 256, 256, 0, stream>>>(
        src, bs, D, Co, Wf[l], Wd[l], Uf, Vf, Ud, Vd);
    int te = BB * Co * NN;
    edge_kernel<<<(te + 255) / 256, 256, 0, stream>>>(idx, Uf, Vf, Ud, Vd, Co,
                                                      L[l].ooff, xcat);
  }

  dvec_kernel<<<(BB * 3 * NN) / 256, 256, 0, stream>>>(xcat, Wd[4], dbuf);
  final_fused_kernel<<<dim3(NT, 6, BB), 256, 0, stream>>>(xcat, Wf[4], dbuf,
                                                          part);
  final_reduce_kernel<<<(BB * 341 * 3 + 255) / 256, 256, 0, stream>>>(
      part, (float*)d_out);
}

// Round 5
// 749.445 us; speedup vs baseline: 2.6094x; 1.2962x over previous
//
#include <hip/hip_runtime.h>
#include <cstddef>

#define BB 8
#define NN 1024
#define KK 20
#define CCAT 169
#define NT 8  // n-tiles of 128 in final fused GEMM

// ---------------- squared norms: xx[b][n] = sum_f cur^2 ----------------
__global__ void xx_kernel(const float* __restrict__ src, int bs, int D,
                          float* __restrict__ xx) {
  int t = blockIdx.x * 256 + threadIdx.x;
  if (t >= BB * NN) return;
  int n = t & (NN - 1);
  int b = t >> 10;
  const float* p = src + (size_t)b * bs + n;
  float s = 0.f;
  int F = 3 * D;
  for (int f = 0; f < F; ++f) {
    float v = p[(size_t)f * NN];
    s += v * v;
  }
  xx[t] = s;
}

// ---------------- neg dist, tiled GEMM-style ----------------
__global__ __launch_bounds__(256) void dist_tile_kernel(
    const float* __restrict__ src, int bs, int F,
    const float* __restrict__ xx, float* __restrict__ dist) {
  __shared__ float As[8][128];
  __shared__ float Bs[8][128];
  int b = blockIdx.z;
  int n0 = blockIdx.y * 128;
  int m0 = blockIdx.x * 128;
  int t = threadIdx.x;
  int tx = t & 15, ty = t >> 4;
  const float* p = src + (size_t)b * bs;

  float acc[8][8];
#pragma unroll
  for (int i = 0; i < 8; ++i)
#pragma unroll
    for (int j = 0; j < 8; ++j) acc[i][j] = 0.f;

  int fr = t >> 5;
  int cc = (t & 31) << 2;
  for (int f0 = 0; f0 < F; f0 += 8) {
    int f = f0 + fr;
    float4 av = {0.f, 0.f, 0.f, 0.f}, bv = {0.f, 0.f, 0.f, 0.f};
    if (f < F) {
      av = *(const float4*)(p + (size_t)f * NN + n0 + cc);
      bv = *(const float4*)(p + (size_t)f * NN + m0 + cc);
    }
    __syncthreads();
    *(float4*)&As[fr][cc] = av;
    *(float4*)&Bs[fr][cc] = bv;
    __syncthreads();
#pragma unroll
    for (int f2 = 0; f2 < 8; ++f2) {
      float4 al = *(const float4*)&As[f2][ty << 2];
      float4 ah = *(const float4*)&As[f2][64 + (ty << 2)];
      float4 bl = *(const float4*)&Bs[f2][tx << 2];
      float4 bh = *(const float4*)&Bs[f2][64 + (tx << 2)];
      float a[8] = {al.x, al.y, al.z, al.w, ah.x, ah.y, ah.z, ah.w};
      float bb[8] = {bl.x, bl.y, bl.z, bl.w, bh.x, bh.y, bh.z, bh.w};
#pragma unroll
      for (int i = 0; i < 8; ++i)
#pragma unroll
        for (int j = 0; j < 8; ++j) acc[i][j] += a[i] * bb[j];
    }
  }

  const float* xb = xx + b * NN;
  float xn[8], xm[8];
#pragma unroll
  for (int i = 0; i < 4; ++i) {
    xn[i] = xb[n0 + (ty << 2) + i];
    xn[4 + i] = xb[n0 + 64 + (ty << 2) + i];
    xm[i] = xb[m0 + (tx << 2) + i];
    xm[4 + i] = xb[m0 + 64 + (tx << 2) + i];
  }
#pragma unroll
  for (int i = 0; i < 8; ++i) {
    int n = n0 + ((i < 4) ? ((ty << 2) + i) : (64 + (ty << 2) + i - 4));
    float* dr = dist + (((size_t)b * NN + n) << 10);
    float4 w0, w1;
    w0.x = 2.f * acc[i][0] - xn[i] - xm[0];
    w0.y = 2.f * acc[i][1] - xn[i] - xm[1];
    w0.z = 2.f * acc[i][2] - xn[i] - xm[2];
    w0.w = 2.f * acc[i][3] - xn[i] - xm[3];
    w1.x = 2.f * acc[i][4] - xn[i] - xm[4];
    w1.y = 2.f * acc[i][5] - xn[i] - xm[5];
    w1.z = 2.f * acc[i][6] - xn[i] - xm[6];
    w1.w = 2.f * acc[i][7] - xn[i] - xm[7];
    *(float4*)(dr + m0 + (tx << 2)) = w0;
    *(float4*)(dr + m0 + 64 + (tx << 2)) = w1;
  }
}

// ---------------- top-k (k=20) per row, one wave per row ----------------
__global__ void topk_kernel(const float* __restrict__ dist,
                            int* __restrict__ idx_out) {
  int wave = threadIdx.x >> 6;
  int lane = threadIdx.x & 63;
  int row = blockIdx.x * 4 + wave;
  const float* d = dist + ((size_t)row << 10);
  float v[16];
  int ix[16];
#pragma unroll
  for (int s = 0; s < 16; ++s) {
    int m = lane + s * 64;
    v[s] = d[m];
    ix[s] = m;
  }
  int* out = idx_out + row * KK;
  for (int r = 0; r < KK; ++r) {
    float bv = -__builtin_inff();
    int bi = NN;
#pragma unroll
    for (int s = 0; s < 16; ++s) {
      if (v[s] > bv || (v[s] == bv && ix[s] < bi)) { bv = v[s]; bi = ix[s]; }
    }
    for (int off = 32; off > 0; off >>= 1) {
      float ov = __shfl_xor(bv, off, 64);
      int oi = __shfl_xor(bi, off, 64);
      if (ov > bv || (ov == bv && oi < bi)) { bv = ov; bi = oi; }
    }
    if (lane == 0) out[r] = bi;
#pragma unroll
    for (int s = 0; s < 16; ++s)
      if (ix[s] == bi) v[s] = -__builtin_inff();
  }
}

// ---------------- transforms: Ufd/Vfd [b][o][c][n] as float2 {f,d} ----------------
__global__ void transform_kernel(const float* __restrict__ src, int bs, int D,
                                 int Co, const float* __restrict__ Wf,
                                 const float* __restrict__ Wd,
                                 float2* __restrict__ Ufd,
                                 float2* __restrict__ Vfd) {
  int t = blockIdx.x * 256 + threadIdx.x;
  int total = BB * Co * 3 * NN;
  if (t >= total) return;
  int n = t & (NN - 1);
  int c = (t >> 10) % 3;
  int o = (t / (3 * NN)) % Co;
  int b = t / (3 * NN * Co);
  const float* p = src + (size_t)b * bs + (size_t)c * NN + n;
  const float* wf = Wf + o * 2 * D;
  const float* wd = Wd + o * 2 * D;
  float uf = 0.f, vf = 0.f, ud = 0.f, vd = 0.f;
  for (int i = 0; i < D; ++i) {
    float s = p[(size_t)i * 3 * NN];
    float af = wf[i], bf = wf[D + i] - af;
    float ad = wd[i], bd = wd[D + i] - ad;
    uf += af * s;
    vf += bf * s;
    ud += ad * s;
    vd += bd * s;
  }
  Ufd[t] = make_float2(uf, ud);
  Vfd[t] = make_float2(vf, vd);
}

// ---------------- edge combine + mean over k, LDS-staged gathers ----------------
// block = (b,o) x n-half; stages Ufd planes (24 KB) into LDS, gathers from LDS.
__global__ __launch_bounds__(256) void edge_kernel(
    const int* __restrict__ idx, const float2* __restrict__ Ufd,
    const float2* __restrict__ Vfd, int Co, int ooff,
    float* __restrict__ xcat) {
  __shared__ float2 Ulds[3 * NN];  // 24 KB
  int bo = blockIdx.x;
  int b = bo / Co, o = bo % Co;
  int t = threadIdx.x;
  size_t base = (size_t)bo * 3 * NN;

  // stage: 3*NN float2 = 1536 float4, 6 per thread, coalesced
  const float4* up = (const float4*)(Ufd + base);
  float4* ul = (float4*)Ulds;
#pragma unroll
  for (int i = 0; i < 6; ++i) ul[t + i * 256] = up[t + i * 256];
  __syncthreads();

  const float inv_k = 1.f / KK;
  int nbase = blockIdx.y * 512;
  for (int rep = 0; rep < 2; ++rep) {
    int n = nbase + rep * 256 + t;
    float2 v0 = Vfd[base + n];
    float2 v1 = Vfd[base + NN + n];
    float2 v2 = Vfd[base + 2 * NN + n];
    const int4* ip = (const int4*)(idx + (b * NN + n) * KK);
    float a0 = 0.f, a1 = 0.f, a2 = 0.f;
#pragma unroll
    for (int q = 0; q < 5; ++q) {
      int4 iv = ip[q];
      int nbs[4] = {iv.x, iv.y, iv.z, iv.w};
#pragma unroll
      for (int jj = 0; jj < 4; ++jj) {
        int nb = nbs[jj];
        float2 u0 = Ulds[nb];
        float2 u1 = Ulds[NN + nb];
        float2 u2 = Ulds[2 * NN + nb];
        float pf0 = u0.x + v0.x, pd0 = u0.y + v0.y;
        float pf1 = u1.x + v1.x, pd1 = u1.y + v1.y;
        float pf2 = u2.x + v2.x, pd2 = u2.y + v2.y;
        float dot = pf0 * pd0 + pf1 * pd1 + pf2 * pd2;
        float dsq = pd0 * pd0 + pd1 * pd1 + pd2 * pd2;
        float g = (dot >= 0.f) ? 0.f : 0.8f * dot / (dsq + 1e-6f);
        a0 += pf0 - g * pd0;
        a1 += pf1 - g * pd1;
        a2 += pf2 - g * pd2;
      }
    }
    size_t ob = (size_t)b * CCAT * 3 * NN + (size_t)(ooff + o) * 3 * NN + n;
    xcat[ob] = a0 * inv_k;
    xcat[ob + NN] = a1 * inv_k;
    xcat[ob + 2 * NN] = a2 * inv_k;
  }
}

// ---------------- final layer d-vector (Cd = 1) ----------------
__global__ void dvec_kernel(const float* __restrict__ xcat,
                            const float* __restrict__ Wd4,
                            float* __restrict__ dbuf) {
  int t = blockIdx.x * 256 + threadIdx.x;
  if (t >= BB * 3 * NN) return;
  int n = t & (NN - 1);
  int c = (t >> 10) % 3;
  int b = t / (3 * NN);
  const float* p = xcat + (size_t)b * CCAT * 3 * NN + (size_t)c * NN + n;
  float s = 0.f;
  for (int i = 0; i < CCAT; ++i) s += Wd4[i] * p[(size_t)i * 3 * NN];
  dbuf[t] = s;
}

// ---------------- fused final GEMM + VN-leakyrelu + partial n-sum ----------------
__global__ __launch_bounds__(256) void final_fused_kernel(
    const float* __restrict__ xcat, const float* __restrict__ Wf4,
    const float* __restrict__ dbuf, float* __restrict__ part) {
  __shared__ float Ws[8][64];
  __shared__ float Xs[3][8][128];
  int b = blockIdx.z;
  int o0 = blockIdx.y * 64;
  int n0 = blockIdx.x * 128;
  int t = threadIdx.x;
  int tx = t & 15, ty = t >> 4;

  float acc[3][4][8];
#pragma unroll
  for (int c = 0; c < 3; ++c)
#pragma unroll
    for (int i = 0; i < 4; ++i)
#pragma unroll
      for (int j = 0; j < 8; ++j) acc[c][i][j] = 0.f;

  const float* xb = xcat + (size_t)b * CCAT * 3 * NN;
  int fr = t >> 5;
  int cc = (t & 31) << 2;
  for (int f0 = 0; f0 < CCAT; f0 += 8) {
    int f = f0 + fr;
    float4 xv[3];
#pragma unroll
    for (int c = 0; c < 3; ++c) {
      xv[c] = make_float4(0.f, 0.f, 0.f, 0.f);
      if (f < CCAT)
        xv[c] = *(const float4*)(xb + ((size_t)f * 3 + c) * NN + n0 + cc);
    }
    float wv[2];
#pragma unroll
    for (int q = 0; q < 2; ++q) {
      int e = t * 2 + q;
      int oo = e & 63, kk = e >> 6;
      int o = o0 + oo, ff = f0 + kk;
      wv[q] = (o < 341 && ff < CCAT) ? Wf4[o * CCAT + ff] : 0.f;
    }
    __syncthreads();
#pragma unroll
    for (int c = 0; c < 3; ++c) *(float4*)&Xs[c][fr][cc] = xv[c];
    {
      int e = t * 2;
      *(float2*)&Ws[e >> 6][e & 63] = make_float2(wv[0], wv[1]);
    }
    __syncthreads();
#pragma unroll
    for (int f2 = 0; f2 < 8; ++f2) {
      float4 w = *(const float4*)&Ws[f2][ty << 2];
      float wa[4] = {w.x, w.y, w.z, w.w};
#pragma unroll
      for (int c = 0; c < 3; ++c) {
        float4 xl = *(const float4*)&Xs[c][f2][tx << 2];
        float4 xh = *(const float4*)&Xs[c][f2][64 + (tx << 2)];
        float xa[8] = {xl.x, xl.y, xl.z, xl.w, xh.x, xh.y, xh.z, xh.w};
#pragma unroll
        for (int i = 0; i < 4; ++i)
#pragma unroll
          for (int j = 0; j < 8; ++j) acc[c][i][j] += wa[i] * xa[j];
      }
    }
  }

  const float* db = dbuf + b * 3 * NN;
  float da[3][8];
#pragma unroll
  for (int c = 0; c < 3; ++c) {
    float4 dl = *(const float4*)(db + c * NN + n0 + (tx << 2));
    float4 dh = *(const float4*)(db + c * NN + n0 + 64 + (tx << 2));
    da[c][0] = dl.x; da[c][1] = dl.y; da[c][2] = dl.z; da[c][3] = dl.w;
    da[c][4] = dh.x; da[c][5] = dh.y; da[c][6] = dh.z; da[c][7] = dh.w;
  }

  float s[3][4];
#pragma unroll
  for (int c = 0; c < 3; ++c)
#pragma unroll
    for (int i = 0; i < 4; ++i) s[c][i] = 0.f;
#pragma unroll
  for (int i = 0; i < 4; ++i) {
#pragma unroll
    for (int j = 0; j < 8; ++j) {
      float d0 = da[0][j], d1 = da[1][j], d2 = da[2][j];
      float p0 = acc[0][i][j], p1 = acc[1][i][j], p2 = acc[2][i][j];
      float dot = p0 * d0 + p1 * d1 + p2 * d2;
      float dsq = d0 * d0 + d1 * d1 + d2 * d2;
      float g = (dot >= 0.f) ? 0.f : 0.8f * dot / (dsq + 1e-6f);
      s[0][i] += p0 - g * d0;
      s[1][i] += p1 - g * d1;
      s[2][i] += p2 - g * d2;
    }
  }

#pragma unroll
  for (int off = 1; off < 16; off <<= 1) {
#pragma unroll
    for (int c = 0; c < 3; ++c)
#pragma unroll
      for (int i = 0; i < 4; ++i) s[c][i] += __shfl_xor(s[c][i], off, 64);
  }
  if (tx == 0) {
#pragma unroll
    for (int i = 0; i < 4; ++i) {
      int o = o0 + (ty << 2) + i;
      if (o < 341) {
#pragma unroll
        for (int c = 0; c < 3; ++c)
          part[(((size_t)b * 341 + o) * 3 + c) * NT + blockIdx.x] = s[c][i];
      }
    }
  }
}

__global__ void final_reduce_kernel(const float* __restrict__ part,
                                    float* __restrict__ out) {
  int t = blockIdx.x * 256 + threadIdx.x;
  if (t >= BB * 341 * 3) return;
  const float* p = part + (size_t)t * NT;
  float s = 0.f;
#pragma unroll
  for (int nt = 0; nt < NT; ++nt) s += p[nt];
  out[t] = s * (1.f / 1024.f);
}

extern "C" void kernel_launch(void* const* d_in, const int* in_sizes, int n_in,
                              void* d_out, int out_size, void* d_ws,
                              size_t ws_size, hipStream_t stream) {
  (void)in_sizes; (void)n_in; (void)out_size; (void)ws_size;
  const float* x = (const float*)d_in[0];
  const float* Wf[5] = {(const float*)d_in[1], (const float*)d_in[3],
                        (const float*)d_in[5], (const float*)d_in[7],
                        (const float*)d_in[9]};
  const float* Wd[5] = {(const float*)d_in[2], (const float*)d_in[4],
                        (const float*)d_in[6], (const float*)d_in[8],
                        (const float*)d_in[10]};

  float* ws = (float*)d_ws;
  float* dist = ws;
  const size_t UVSZ = (size_t)BB * 85 * 3 * NN;  // per-buffer float2 count
  float2* Ufd = (float2*)ws;
  float2* Vfd = Ufd + UVSZ;
  float* part = ws;  // dist/UV region is dead by the time part is written
  size_t off = (size_t)BB * NN * NN;
  int* idx = (int*)(ws + off);
  off += (size_t)BB * NN * KK;
  float* xx = ws + off;
  off += (size_t)BB * NN;
  float* xcat = ws + off;
  off += (size_t)BB * CCAT * 3 * NN;
  float* dbuf = ws + off;

  struct LayerCfg { int D, Co, inoff, ooff; };
  const LayerCfg L[4] = {
      {1, 21, 0, 0},
      {21, 21, 0, 21},
      {21, 42, 21, 42},
      {42, 85, 42, 84},
  };

  for (int l = 0; l < 4; ++l) {
    const float* src = (l == 0) ? x : (xcat + (size_t)L[l].inoff * 3 * NN);
    int bs = (l == 0) ? 3 * NN : CCAT * 3 * NN;
    int D = L[l].D, Co = L[l].Co;

    xx_kernel<<<(BB * NN) / 256, 256, 0, stream>>>(src, bs, D, xx);
    dist_tile_kernel<<<dim3(8, 8, BB), 256, 0, stream>>>(src, bs, 3 * D, xx,
                                                         dist);
    topk_kernel<<<(BB * NN) / 4, 256, 0, stream>>>(dist, idx);
    int tt = BB * Co * 3 * NN;
    transform_kernel<<<(tt + 255) / 256, 256, 0, stream>>>(
        src, bs, D, Co, Wf[l], Wd[l], Ufd, Vfd);
    edge_kernel<<<dim3(BB * Co, 2), 256, 0, stream>>>(idx, Ufd, Vfd, Co,
                                                      L[l].ooff, xcat);
  }

  dvec_kernel<<<(BB * 3 * NN) / 256, 256, 0, stream>>>(xcat, Wd[4], dbuf);
  final_fused_kernel<<<dim3(NT, 6, BB), 256, 0, stream>>>(xcat, Wf[4], dbuf,
                                                          part);
  final_reduce_kernel<<<(BB * 341 * 3 + 255) / 256, 256, 0, stream>>>(
      part, (float*)d_out);
}

// Round 6
// 701.126 us; speedup vs baseline: 2.7892x; 1.0689x over previous
//
#include <hip/hip_runtime.h>
#include <cstddef>

#define BB 8
#define NN 1024
#define KK 20
#define CCAT 169
#define NT 16  // n-tiles of 64 in final fused GEMM

// ---------------- squared norms: xx[b][n] = sum_f cur^2 ----------------
__global__ void xx_kernel(const float* __restrict__ src, int bs, int D,
                          float* __restrict__ xx) {
  int t = blockIdx.x * 256 + threadIdx.x;
  if (t >= BB * NN) return;
  int n = t & (NN - 1);
  int b = t >> 10;
  const float* p = src + (size_t)b * bs + n;
  float s = 0.f;
  int F = 3 * D;
  for (int f = 0; f < F; ++f) {
    float v = p[(size_t)f * NN];
    s += v * v;
  }
  xx[t] = s;
}

// ---------------- neg dist, tiled GEMM-style ----------------
__global__ __launch_bounds__(256) void dist_tile_kernel(
    const float* __restrict__ src, int bs, int F,
    const float* __restrict__ xx, float* __restrict__ dist) {
  __shared__ float As[8][128];
  __shared__ float Bs[8][128];
  int b = blockIdx.z;
  int n0 = blockIdx.y * 128;
  int m0 = blockIdx.x * 128;
  int t = threadIdx.x;
  int tx = t & 15, ty = t >> 4;
  const float* p = src + (size_t)b * bs;

  float acc[8][8];
#pragma unroll
  for (int i = 0; i < 8; ++i)
#pragma unroll
    for (int j = 0; j < 8; ++j) acc[i][j] = 0.f;

  int fr = t >> 5;
  int cc = (t & 31) << 2;
  for (int f0 = 0; f0 < F; f0 += 8) {
    int f = f0 + fr;
    float4 av = {0.f, 0.f, 0.f, 0.f}, bv = {0.f, 0.f, 0.f, 0.f};
    if (f < F) {
      av = *(const float4*)(p + (size_t)f * NN + n0 + cc);
      bv = *(const float4*)(p + (size_t)f * NN + m0 + cc);
    }
    __syncthreads();
    *(float4*)&As[fr][cc] = av;
    *(float4*)&Bs[fr][cc] = bv;
    __syncthreads();
#pragma unroll
    for (int f2 = 0; f2 < 8; ++f2) {
      float4 al = *(const float4*)&As[f2][ty << 2];
      float4 ah = *(const float4*)&As[f2][64 + (ty << 2)];
      float4 bl = *(const float4*)&Bs[f2][tx << 2];
      float4 bh = *(const float4*)&Bs[f2][64 + (tx << 2)];
      float a[8] = {al.x, al.y, al.z, al.w, ah.x, ah.y, ah.z, ah.w};
      float bb[8] = {bl.x, bl.y, bl.z, bl.w, bh.x, bh.y, bh.z, bh.w};
#pragma unroll
      for (int i = 0; i < 8; ++i)
#pragma unroll
        for (int j = 0; j < 8; ++j) acc[i][j] += a[i] * bb[j];
    }
  }

  const float* xb = xx + b * NN;
  float xn[8], xm[8];
#pragma unroll
  for (int i = 0; i < 4; ++i) {
    xn[i] = xb[n0 + (ty << 2) + i];
    xn[4 + i] = xb[n0 + 64 + (ty << 2) + i];
    xm[i] = xb[m0 + (tx << 2) + i];
    xm[4 + i] = xb[m0 + 64 + (tx << 2) + i];
  }
#pragma unroll
  for (int i = 0; i < 8; ++i) {
    int n = n0 + ((i < 4) ? ((ty << 2) + i) : (64 + (ty << 2) + i - 4));
    float* dr = dist + (((size_t)b * NN + n) << 10);
    float4 w0, w1;
    w0.x = 2.f * acc[i][0] - xn[i] - xm[0];
    w0.y = 2.f * acc[i][1] - xn[i] - xm[1];
    w0.z = 2.f * acc[i][2] - xn[i] - xm[2];
    w0.w = 2.f * acc[i][3] - xn[i] - xm[3];
    w1.x = 2.f * acc[i][4] - xn[i] - xm[4];
    w1.y = 2.f * acc[i][5] - xn[i] - xm[5];
    w1.z = 2.f * acc[i][6] - xn[i] - xm[6];
    w1.w = 2.f * acc[i][7] - xn[i] - xm[7];
    *(float4*)(dr + m0 + (tx << 2)) = w0;
    *(float4*)(dr + m0 + 64 + (tx << 2)) = w1;
  }
}

// ---------------- top-k (k=20) per row, one wave per row ----------------
__global__ void topk_kernel(const float* __restrict__ dist,
                            int* __restrict__ idx_out) {
  int wave = threadIdx.x >> 6;
  int lane = threadIdx.x & 63;
  int row = blockIdx.x * 4 + wave;
  const float* d = dist + ((size_t)row << 10);
  float v[16];
  int ix[16];
#pragma unroll
  for (int s = 0; s < 16; ++s) {
    int m = lane + s * 64;
    v[s] = d[m];
    ix[s] = m;
  }
  int* out = idx_out + row * KK;
  for (int r = 0; r < KK; ++r) {
    float bv = -__builtin_inff();
    int bi = NN;
#pragma unroll
    for (int s = 0; s < 16; ++s) {
      if (v[s] > bv || (v[s] == bv && ix[s] < bi)) { bv = v[s]; bi = ix[s]; }
    }
    for (int off = 32; off > 0; off >>= 1) {
      float ov = __shfl_xor(bv, off, 64);
      int oi = __shfl_xor(bi, off, 64);
      if (ov > bv || (ov == bv && oi < bi)) { bv = ov; bi = oi; }
    }
    if (lane == 0) out[r] = bi;
#pragma unroll
    for (int s = 0; s < 16; ++s)
      if (ix[s] == bi) v[s] = -__builtin_inff();
  }
}

// ---------------- transforms: Ufd/Vfd [b][o][c][n] as float2 {f,d} ----------------
__global__ void transform_kernel(const float* __restrict__ src, int bs, int D,
                                 int Co, const float* __restrict__ Wf,
                                 const float* __restrict__ Wd,
                                 float2* __restrict__ Ufd,
                                 float2* __restrict__ Vfd) {
  int t = blockIdx.x * 256 + threadIdx.x;
  int total = BB * Co * 3 * NN;
  if (t >= total) return;
  int n = t & (NN - 1);
  int c = (t >> 10) % 3;
  int o = (t / (3 * NN)) % Co;
  int b = t / (3 * NN * Co);
  const float* p = src + (size_t)b * bs + (size_t)c * NN + n;
  const float* wf = Wf + o * 2 * D;
  const float* wd = Wd + o * 2 * D;
  float uf = 0.f, vf = 0.f, ud = 0.f, vd = 0.f;
  for (int i = 0; i < D; ++i) {
    float s = p[(size_t)i * 3 * NN];
    float af = wf[i], bf = wf[D + i] - af;
    float ad = wd[i], bd = wd[D + i] - ad;
    uf += af * s;
    vf += bf * s;
    ud += ad * s;
    vd += bd * s;
  }
  Ufd[t] = make_float2(uf, ud);
  Vfd[t] = make_float2(vf, vd);
}

// ---------------- edge combine + mean over k, LDS-staged gathers ----------------
__global__ __launch_bounds__(256) void edge_kernel(
    const int* __restrict__ idx, const float2* __restrict__ Ufd,
    const float2* __restrict__ Vfd, int Co, int ooff,
    float* __restrict__ xcat) {
  __shared__ float2 Ulds[3 * NN];  // 24 KB
  int bo = blockIdx.x;
  int b = bo / Co, o = bo % Co;
  int t = threadIdx.x;
  size_t base = (size_t)bo * 3 * NN;

  const float4* up = (const float4*)(Ufd + base);
  float4* ul = (float4*)Ulds;
#pragma unroll
  for (int i = 0; i < 6; ++i) ul[t + i * 256] = up[t + i * 256];
  __syncthreads();

  const float inv_k = 1.f / KK;
  int nbase = blockIdx.y * 512;
  for (int rep = 0; rep < 2; ++rep) {
    int n = nbase + rep * 256 + t;
    float2 v0 = Vfd[base + n];
    float2 v1 = Vfd[base + NN + n];
    float2 v2 = Vfd[base + 2 * NN + n];
    const int4* ip = (const int4*)(idx + (b * NN + n) * KK);
    float a0 = 0.f, a1 = 0.f, a2 = 0.f;
#pragma unroll
    for (int q = 0; q < 5; ++q) {
      int4 iv = ip[q];
      int nbs[4] = {iv.x, iv.y, iv.z, iv.w};
#pragma unroll
      for (int jj = 0; jj < 4; ++jj) {
        int nb = nbs[jj];
        float2 u0 = Ulds[nb];
        float2 u1 = Ulds[NN + nb];
        float2 u2 = Ulds[2 * NN + nb];
        float pf0 = u0.x + v0.x, pd0 = u0.y + v0.y;
        float pf1 = u1.x + v1.x, pd1 = u1.y + v1.y;
        float pf2 = u2.x + v2.x, pd2 = u2.y + v2.y;
        float dot = pf0 * pd0 + pf1 * pd1 + pf2 * pd2;
        float dsq = pd0 * pd0 + pd1 * pd1 + pd2 * pd2;
        float g = (dot >= 0.f) ? 0.f : 0.8f * dot / (dsq + 1e-6f);
        a0 += pf0 - g * pd0;
        a1 += pf1 - g * pd1;
        a2 += pf2 - g * pd2;
      }
    }
    size_t ob = (size_t)b * CCAT * 3 * NN + (size_t)(ooff + o) * 3 * NN + n;
    xcat[ob] = a0 * inv_k;
    xcat[ob + NN] = a1 * inv_k;
    xcat[ob + 2 * NN] = a2 * inv_k;
  }
}

// ---------------- fused final GEMM + dvec + VN-leakyrelu + partial n-sum ----------------
// Tile: 64 o x 64 n per block, all 3 c-planes; K=169 staged in chunks of 16.
// dvec (Cd=1) is computed in-loop: dv[c][n] = sum_f Wd4[f]*xcat[f][c][n].
// part[((b*341+o)*3+c)*NT + ntile] = sum over this n-tile.
__global__ __launch_bounds__(256) void final_fused_kernel(
    const float* __restrict__ xcat, const float* __restrict__ Wf4,
    const float* __restrict__ Wd4, float* __restrict__ part) {
  __shared__ float Ws[16][64];
  __shared__ float Xs[3][16][64];
  __shared__ float Wds[16];
  int b = blockIdx.z;
  int o0 = blockIdx.y * 64;
  int n0 = blockIdx.x * 64;
  int t = threadIdx.x;
  int tx = t & 15, ty = t >> 4;

  float acc[3][4][4];  // [c][o_i][n_j]
  float dv[3][4];      // [c][n_j]
#pragma unroll
  for (int c = 0; c < 3; ++c) {
#pragma unroll
    for (int i = 0; i < 4; ++i)
#pragma unroll
      for (int j = 0; j < 4; ++j) acc[c][i][j] = 0.f;
#pragma unroll
    for (int j = 0; j < 4; ++j) dv[c][j] = 0.f;
  }

  const float* xb = xcat + (size_t)b * CCAT * 3 * NN;
  for (int f0 = 0; f0 < CCAT; f0 += 16) {
    int f = f0 + ty;  // this thread's staging row
    float4 xv[3];
#pragma unroll
    for (int c = 0; c < 3; ++c) {
      xv[c] = make_float4(0.f, 0.f, 0.f, 0.f);
      if (f < CCAT)
        xv[c] = *(const float4*)(xb + ((size_t)f * 3 + c) * NN + n0 + (tx << 2));
    }
    float wv[4];
#pragma unroll
    for (int q = 0; q < 4; ++q) {
      int o = o0 + (tx << 2) + q;
      wv[q] = (o < 341 && f < CCAT) ? Wf4[o * CCAT + f] : 0.f;
    }
    float wdv = 0.f;
    if (t < 16 && f0 + t < CCAT) wdv = Wd4[f0 + t];
    __syncthreads();
#pragma unroll
    for (int c = 0; c < 3; ++c) *(float4*)&Xs[c][ty][tx << 2] = xv[c];
    *(float4*)&Ws[ty][tx << 2] = make_float4(wv[0], wv[1], wv[2], wv[3]);
    if (t < 16) Wds[t] = wdv;
    __syncthreads();
#pragma unroll
    for (int f2 = 0; f2 < 16; ++f2) {
      float4 w = *(const float4*)&Ws[f2][ty << 2];
      float wa[4] = {w.x, w.y, w.z, w.w};
      float wd = Wds[f2];
#pragma unroll
      for (int c = 0; c < 3; ++c) {
        float4 x = *(const float4*)&Xs[c][f2][tx << 2];
        float xa[4] = {x.x, x.y, x.z, x.w};
#pragma unroll
        for (int j = 0; j < 4; ++j) dv[c][j] += wd * xa[j];
#pragma unroll
        for (int i = 0; i < 4; ++i)
#pragma unroll
          for (int j = 0; j < 4; ++j) acc[c][i][j] += wa[i] * xa[j];
      }
    }
  }

  float s[3][4];
#pragma unroll
  for (int c = 0; c < 3; ++c)
#pragma unroll
    for (int i = 0; i < 4; ++i) s[c][i] = 0.f;
#pragma unroll
  for (int i = 0; i < 4; ++i) {
#pragma unroll
    for (int j = 0; j < 4; ++j) {
      float d0 = dv[0][j], d1 = dv[1][j], d2 = dv[2][j];
      float p0 = acc[0][i][j], p1 = acc[1][i][j], p2 = acc[2][i][j];
      float dot = p0 * d0 + p1 * d1 + p2 * d2;
      float dsq = d0 * d0 + d1 * d1 + d2 * d2;
      float g = (dot >= 0.f) ? 0.f : 0.8f * dot / (dsq + 1e-6f);
      s[0][i] += p0 - g * d0;
      s[1][i] += p1 - g * d1;
      s[2][i] += p2 - g * d2;
    }
  }

  // reduce across tx (lane bits [3:0] within each wave)
#pragma unroll
  for (int off = 1; off < 16; off <<= 1) {
#pragma unroll
    for (int c = 0; c < 3; ++c)
#pragma unroll
      for (int i = 0; i < 4; ++i) s[c][i] += __shfl_xor(s[c][i], off, 64);
  }
  if (tx == 0) {
#pragma unroll
    for (int i = 0; i < 4; ++i) {
      int o = o0 + (ty << 2) + i;
      if (o < 341) {
#pragma unroll
        for (int c = 0; c < 3; ++c)
          part[(((size_t)b * 341 + o) * 3 + c) * NT + blockIdx.x] = s[c][i];
      }
    }
  }
}

__global__ void final_reduce_kernel(const float* __restrict__ part,
                                    float* __restrict__ out) {
  int t = blockIdx.x * 256 + threadIdx.x;
  if (t >= BB * 341 * 3) return;
  const float* p = part + (size_t)t * NT;
  float s = 0.f;
#pragma unroll
  for (int nt = 0; nt < NT; ++nt) s += p[nt];
  out[t] = s * (1.f / 1024.f);
}

extern "C" void kernel_launch(void* const* d_in, const int* in_sizes, int n_in,
                              void* d_out, int out_size, void* d_ws,
                              size_t ws_size, hipStream_t stream) {
  (void)in_sizes; (void)n_in; (void)out_size; (void)ws_size;
  const float* x = (const float*)d_in[0];
  const float* Wf[5] = {(const float*)d_in[1], (const float*)d_in[3],
                        (const float*)d_in[5], (const float*)d_in[7],
                        (const float*)d_in[9]};
  const float* Wd[5] = {(const float*)d_in[2], (const float*)d_in[4],
                        (const float*)d_in[6], (const float*)d_in[8],
                        (const float*)d_in[10]};

  float* ws = (float*)d_ws;
  float* dist = ws;
  const size_t UVSZ = (size_t)BB * 85 * 3 * NN;  // per-buffer float2 count
  float2* Ufd = (float2*)ws;
  float2* Vfd = Ufd + UVSZ;
  float* part = ws;  // dist/UV region is dead by the time part is written
  size_t off = (size_t)BB * NN * NN;
  int* idx = (int*)(ws + off);
  off += (size_t)BB * NN * KK;
  float* xx = ws + off;
  off += (size_t)BB * NN;
  float* xcat = ws + off;

  struct LayerCfg { int D, Co, inoff, ooff; };
  const LayerCfg L[4] = {
      {1, 21, 0, 0},
      {21, 21, 0, 21},
      {21, 42, 21, 42},
      {42, 85, 42, 84},
  };

  for (int l = 0; l < 4; ++l) {
    const float* src = (l == 0) ? x : (xcat + (size_t)L[l].inoff * 3 * NN);
    int bs = (l == 0) ? 3 * NN : CCAT * 3 * NN;
    int D = L[l].D, Co = L[l].Co;

    xx_kernel<<<(BB * NN) / 256, 256, 0, stream>>>(src, bs, D, xx);
    dist_tile_kernel<<<dim3(8, 8, BB), 256, 0, stream>>>(src, bs, 3 * D, xx,
                                                         dist);
    topk_kernel<<<(BB * NN) / 4, 256, 0, stream>>>(dist, idx);
    int tt = BB * Co * 3 * NN;
    transform_kernel<<<(tt + 255) / 256, 256, 0, stream>>>(
        src, bs, D, Co, Wf[l], Wd[l], Ufd, Vfd);
    edge_kernel<<<dim3(BB * Co, 2), 256, 0, stream>>>(idx, Ufd, Vfd, Co,
                                                      L[l].ooff, xcat);
  }

  final_fused_kernel<<<dim3(NT, 6, BB), 256, 0, stream>>>(xcat, Wf[4], Wd[4],
                                                          part);
  final_reduce_kernel<<<(BB * 341 * 3 + 255) / 256, 256, 0, stream>>>(
      part, (float*)d_out);
}

// Round 7
// 580.742 us; speedup vs baseline: 3.3674x; 1.2073x over previous
//
#include <hip/hip_runtime.h>
#include <cstddef>

#define BB 8
#define NN 1024
#define KK 20
#define CCAT 169
#define NT 16  // n-tiles of 64 in final fused GEMM

// ---------------- neg dist, tiled GEMM-style, norms fused in ----------------
// dist[b][n][m] = 2*sum_f x[f][n]*x[f][m] - ||x_n||^2 - ||x_m||^2
__global__ __launch_bounds__(256) void dist_tile_kernel(
    const float* __restrict__ src, int bs, int F, float* __restrict__ dist) {
  __shared__ float As[8][128];
  __shared__ float Bs[8][128];
  int b = blockIdx.z;
  int n0 = blockIdx.y * 128;
  int m0 = blockIdx.x * 128;
  int t = threadIdx.x;
  int tx = t & 15, ty = t >> 4;
  const float* p = src + (size_t)b * bs;

  float acc[8][8];
  float xn[8], xm[8];
#pragma unroll
  for (int i = 0; i < 8; ++i) {
    xn[i] = 0.f;
    xm[i] = 0.f;
#pragma unroll
    for (int j = 0; j < 8; ++j) acc[i][j] = 0.f;
  }

  int fr = t >> 5;
  int cc = (t & 31) << 2;
  for (int f0 = 0; f0 < F; f0 += 8) {
    int f = f0 + fr;
    float4 av = {0.f, 0.f, 0.f, 0.f}, bv = {0.f, 0.f, 0.f, 0.f};
    if (f < F) {
      av = *(const float4*)(p + (size_t)f * NN + n0 + cc);
      bv = *(const float4*)(p + (size_t)f * NN + m0 + cc);
    }
    __syncthreads();
    *(float4*)&As[fr][cc] = av;
    *(float4*)&Bs[fr][cc] = bv;
    __syncthreads();
#pragma unroll
    for (int f2 = 0; f2 < 8; ++f2) {
      float4 al = *(const float4*)&As[f2][ty << 2];
      float4 ah = *(const float4*)&As[f2][64 + (ty << 2)];
      float4 bl = *(const float4*)&Bs[f2][tx << 2];
      float4 bh = *(const float4*)&Bs[f2][64 + (tx << 2)];
      float a[8] = {al.x, al.y, al.z, al.w, ah.x, ah.y, ah.z, ah.w};
      float bb[8] = {bl.x, bl.y, bl.z, bl.w, bh.x, bh.y, bh.z, bh.w};
#pragma unroll
      for (int i = 0; i < 8; ++i) xn[i] += a[i] * a[i];
#pragma unroll
      for (int j = 0; j < 8; ++j) xm[j] += bb[j] * bb[j];
#pragma unroll
      for (int i = 0; i < 8; ++i)
#pragma unroll
        for (int j = 0; j < 8; ++j) acc[i][j] += a[i] * bb[j];
    }
  }

#pragma unroll
  for (int i = 0; i < 8; ++i) {
    int n = n0 + ((i < 4) ? ((ty << 2) + i) : (64 + (ty << 2) + i - 4));
    float* dr = dist + (((size_t)b * NN + n) << 10);
    float4 w0, w1;
    w0.x = 2.f * acc[i][0] - xn[i] - xm[0];
    w0.y = 2.f * acc[i][1] - xn[i] - xm[1];
    w0.z = 2.f * acc[i][2] - xn[i] - xm[2];
    w0.w = 2.f * acc[i][3] - xn[i] - xm[3];
    w1.x = 2.f * acc[i][4] - xn[i] - xm[4];
    w1.y = 2.f * acc[i][5] - xn[i] - xm[5];
    w1.z = 2.f * acc[i][6] - xn[i] - xm[6];
    w1.w = 2.f * acc[i][7] - xn[i] - xm[7];
    *(float4*)(dr + m0 + (tx << 2)) = w0;
    *(float4*)(dr + m0 + 64 + (tx << 2)) = w1;
  }
}

// ---------------- top-k (k=20) per row, one wave per row ----------------
__global__ void topk_kernel(const float* __restrict__ dist,
                            int* __restrict__ idx_out) {
  int wave = threadIdx.x >> 6;
  int lane = threadIdx.x & 63;
  int row = blockIdx.x * 4 + wave;
  const float* d = dist + ((size_t)row << 10);
  float v[16];
  int ix[16];
#pragma unroll
  for (int s = 0; s < 16; ++s) {
    int m = lane + s * 64;
    v[s] = d[m];
    ix[s] = m;
  }
  int* out = idx_out + row * KK;
  for (int r = 0; r < KK; ++r) {
    float bv = -__builtin_inff();
    int bi = NN;
#pragma unroll
    for (int s = 0; s < 16; ++s) {
      if (v[s] > bv || (v[s] == bv && ix[s] < bi)) { bv = v[s]; bi = ix[s]; }
    }
    for (int off = 32; off > 0; off >>= 1) {
      float ov = __shfl_xor(bv, off, 64);
      int oi = __shfl_xor(bi, off, 64);
      if (ov > bv || (ov == bv && oi < bi)) { bv = ov; bi = oi; }
    }
    if (lane == 0) out[r] = bi;
#pragma unroll
    for (int s = 0; s < 16; ++s)
      if (ix[s] == bi) v[s] = -__builtin_inff();
  }
}

// ---------------- fused transform + edge combine + mean over k ----------------
// One block per (b,o). Phase A: compute U{f,d},V{f,d}[c][n] from src with
// block-uniform weight row o, into LDS. Phase B: k=20 LDS gathers + VN
// nonlinearity + mean, write xcat slice.
__global__ __launch_bounds__(256) void edge_fused_kernel(
    const float* __restrict__ src, int bs, int D, int Co,
    const float* __restrict__ Wf, const float* __restrict__ Wd,
    const int* __restrict__ idx, int ooff, float* __restrict__ xcat) {
  __shared__ float2 Ulds[3 * NN];  // 24 KB {Uf,Ud}
  __shared__ float2 Vlds[3 * NN];  // 24 KB {Vf,Vd}
  __shared__ float4 Wlds[48];      // {wfa, wfb, wda, wdb} per i, D<=42
  int bo = blockIdx.x;
  int b = bo / Co, o = bo % Co;
  int t = threadIdx.x;

  if (t < D) {
    float wfa = Wf[o * 2 * D + t];
    float wfb = Wf[o * 2 * D + D + t] - wfa;
    float wda = Wd[o * 2 * D + t];
    float wdb = Wd[o * 2 * D + D + t] - wda;
    Wlds[t] = make_float4(wfa, wfb, wda, wdb);
  }
  __syncthreads();

  const float* sb = src + (size_t)b * bs;
  // phase A: 768 float4-groups over the 3*NN positions, 3 per thread
#pragma unroll
  for (int r = 0; r < 3; ++r) {
    int g = t + 256 * r;
    float4 uf = {0.f, 0.f, 0.f, 0.f}, vf = {0.f, 0.f, 0.f, 0.f};
    float4 ud = {0.f, 0.f, 0.f, 0.f}, vd = {0.f, 0.f, 0.f, 0.f};
    for (int i = 0; i < D; ++i) {
      float4 s = *(const float4*)(sb + (size_t)i * 3 * NN + (g << 2));
      float4 w = Wlds[i];
      uf.x += w.x * s.x; uf.y += w.x * s.y; uf.z += w.x * s.z; uf.w += w.x * s.w;
      vf.x += w.y * s.x; vf.y += w.y * s.y; vf.z += w.y * s.z; vf.w += w.y * s.w;
      ud.x += w.z * s.x; ud.y += w.z * s.y; ud.z += w.z * s.z; ud.w += w.z * s.w;
      vd.x += w.w * s.x; vd.y += w.w * s.y; vd.z += w.w * s.z; vd.w += w.w * s.w;
    }
    *(float4*)&Ulds[(g << 2) + 0] = make_float4(uf.x, ud.x, uf.y, ud.y);
    *(float4*)&Ulds[(g << 2) + 2] = make_float4(uf.z, ud.z, uf.w, ud.w);
    *(float4*)&Vlds[(g << 2) + 0] = make_float4(vf.x, vd.x, vf.y, vd.y);
    *(float4*)&Vlds[(g << 2) + 2] = make_float4(vf.z, vd.z, vf.w, vd.w);
  }
  __syncthreads();

  const float inv_k = 1.f / KK;
  // phase B: all 1024 n, 4 per thread
#pragma unroll
  for (int rep = 0; rep < 4; ++rep) {
    int n = rep * 256 + t;
    float2 v0 = Vlds[n];
    float2 v1 = Vlds[NN + n];
    float2 v2 = Vlds[2 * NN + n];
    const int4* ip = (const int4*)(idx + (b * NN + n) * KK);
    float a0 = 0.f, a1 = 0.f, a2 = 0.f;
#pragma unroll
    for (int q = 0; q < 5; ++q) {
      int4 iv = ip[q];
      int nbs[4] = {iv.x, iv.y, iv.z, iv.w};
#pragma unroll
      for (int jj = 0; jj < 4; ++jj) {
        int nb = nbs[jj];
        float2 u0 = Ulds[nb];
        float2 u1 = Ulds[NN + nb];
        float2 u2 = Ulds[2 * NN + nb];
        float pf0 = u0.x + v0.x, pd0 = u0.y + v0.y;
        float pf1 = u1.x + v1.x, pd1 = u1.y + v1.y;
        float pf2 = u2.x + v2.x, pd2 = u2.y + v2.y;
        float dot = pf0 * pd0 + pf1 * pd1 + pf2 * pd2;
        float dsq = pd0 * pd0 + pd1 * pd1 + pd2 * pd2;
        float g = (dot >= 0.f) ? 0.f : 0.8f * dot / (dsq + 1e-6f);
        a0 += pf0 - g * pd0;
        a1 += pf1 - g * pd1;
        a2 += pf2 - g * pd2;
      }
    }
    size_t ob = (size_t)b * CCAT * 3 * NN + (size_t)(ooff + o) * 3 * NN + n;
    xcat[ob] = a0 * inv_k;
    xcat[ob + NN] = a1 * inv_k;
    xcat[ob + 2 * NN] = a2 * inv_k;
  }
}

// ---------------- fused final GEMM + dvec + VN-leakyrelu + partial n-sum ----------------
__global__ __launch_bounds__(256) void final_fused_kernel(
    const float* __restrict__ xcat, const float* __restrict__ Wf4,
    const float* __restrict__ Wd4, float* __restrict__ part) {
  __shared__ float Ws[16][64];
  __shared__ float Xs[3][16][64];
  __shared__ float Wds[16];
  int b = blockIdx.z;
  int o0 = blockIdx.y * 64;
  int n0 = blockIdx.x * 64;
  int t = threadIdx.x;
  int tx = t & 15, ty = t >> 4;

  float acc[3][4][4];  // [c][o_i][n_j]
  float dv[3][4];      // [c][n_j]
#pragma unroll
  for (int c = 0; c < 3; ++c) {
#pragma unroll
    for (int i = 0; i < 4; ++i)
#pragma unroll
      for (int j = 0; j < 4; ++j) acc[c][i][j] = 0.f;
#pragma unroll
    for (int j = 0; j < 4; ++j) dv[c][j] = 0.f;
  }

  const float* xb = xcat + (size_t)b * CCAT * 3 * NN;
  for (int f0 = 0; f0 < CCAT; f0 += 16) {
    int f = f0 + ty;
    float4 xv[3];
#pragma unroll
    for (int c = 0; c < 3; ++c) {
      xv[c] = make_float4(0.f, 0.f, 0.f, 0.f);
      if (f < CCAT)
        xv[c] = *(const float4*)(xb + ((size_t)f * 3 + c) * NN + n0 + (tx << 2));
    }
    float wv[4];
#pragma unroll
    for (int q = 0; q < 4; ++q) {
      int o = o0 + (tx << 2) + q;
      wv[q] = (o < 341 && f < CCAT) ? Wf4[o * CCAT + f] : 0.f;
    }
    float wdv = 0.f;
    if (t < 16 && f0 + t < CCAT) wdv = Wd4[f0 + t];
    __syncthreads();
#pragma unroll
    for (int c = 0; c < 3; ++c) *(float4*)&Xs[c][ty][tx << 2] = xv[c];
    *(float4*)&Ws[ty][tx << 2] = make_float4(wv[0], wv[1], wv[2], wv[3]);
    if (t < 16) Wds[t] = wdv;
    __syncthreads();
#pragma unroll
    for (int f2 = 0; f2 < 16; ++f2) {
      float4 w = *(const float4*)&Ws[f2][ty << 2];
      float wa[4] = {w.x, w.y, w.z, w.w};
      float wd = Wds[f2];
#pragma unroll
      for (int c = 0; c < 3; ++c) {
        float4 x = *(const float4*)&Xs[c][f2][tx << 2];
        float xa[4] = {x.x, x.y, x.z, x.w};
#pragma unroll
        for (int j = 0; j < 4; ++j) dv[c][j] += wd * xa[j];
#pragma unroll
        for (int i = 0; i < 4; ++i)
#pragma unroll
          for (int j = 0; j < 4; ++j) acc[c][i][j] += wa[i] * xa[j];
      }
    }
  }

  float s[3][4];
#pragma unroll
  for (int c = 0; c < 3; ++c)
#pragma unroll
    for (int i = 0; i < 4; ++i) s[c][i] = 0.f;
#pragma unroll
  for (int i = 0; i < 4; ++i) {
#pragma unroll
    for (int j = 0; j < 4; ++j) {
      float d0 = dv[0][j], d1 = dv[1][j], d2 = dv[2][j];
      float p0 = acc[0][i][j], p1 = acc[1][i][j], p2 = acc[2][i][j];
      float dot = p0 * d0 + p1 * d1 + p2 * d2;
      float dsq = d0 * d0 + d1 * d1 + d2 * d2;
      float g = (dot >= 0.f) ? 0.f : 0.8f * dot / (dsq + 1e-6f);
      s[0][i] += p0 - g * d0;
      s[1][i] += p1 - g * d1;
      s[2][i] += p2 - g * d2;
    }
  }

#pragma unroll
  for (int off = 1; off < 16; off <<= 1) {
#pragma unroll
    for (int c = 0; c < 3; ++c)
#pragma unroll
      for (int i = 0; i < 4; ++i) s[c][i] += __shfl_xor(s[c][i], off, 64);
  }
  if (tx == 0) {
#pragma unroll
    for (int i = 0; i < 4; ++i) {
      int o = o0 + (ty << 2) + i;
      if (o < 341) {
#pragma unroll
        for (int c = 0; c < 3; ++c)
          part[(((size_t)b * 341 + o) * 3 + c) * NT + blockIdx.x] = s[c][i];
      }
    }
  }
}

__global__ void final_reduce_kernel(const float* __restrict__ part,
                                    float* __restrict__ out) {
  int t = blockIdx.x * 256 + threadIdx.x;
  if (t >= BB * 341 * 3) return;
  const float* p = part + (size_t)t * NT;
  float s = 0.f;
#pragma unroll
  for (int nt = 0; nt < NT; ++nt) s += p[nt];
  out[t] = s * (1.f / 1024.f);
}

extern "C" void kernel_launch(void* const* d_in, const int* in_sizes, int n_in,
                              void* d_out, int out_size, void* d_ws,
                              size_t ws_size, hipStream_t stream) {
  (void)in_sizes; (void)n_in; (void)out_size; (void)ws_size;
  const float* x = (const float*)d_in[0];
  const float* Wf[5] = {(const float*)d_in[1], (const float*)d_in[3],
                        (const float*)d_in[5], (const float*)d_in[7],
                        (const float*)d_in[9]};
  const float* Wd[5] = {(const float*)d_in[2], (const float*)d_in[4],
                        (const float*)d_in[6], (const float*)d_in[8],
                        (const float*)d_in[10]};

  float* ws = (float*)d_ws;
  float* dist = ws;
  float* part = ws;  // dist region dead once final_fused runs
  size_t off = (size_t)BB * NN * NN;
  int* idx = (int*)(ws + off);
  off += (size_t)BB * NN * KK;
  float* xcat = ws + off;

  struct LayerCfg { int D, Co, inoff, ooff; };
  const LayerCfg L[4] = {
      {1, 21, 0, 0},
      {21, 21, 0, 21},
      {21, 42, 21, 42},
      {42, 85, 42, 84},
  };

  for (int l = 0; l < 4; ++l) {
    const float* src = (l == 0) ? x : (xcat + (size_t)L[l].inoff * 3 * NN);
    int bs = (l == 0) ? 3 * NN : CCAT * 3 * NN;
    int D = L[l].D, Co = L[l].Co;

    dist_tile_kernel<<<dim3(8, 8, BB), 256, 0, stream>>>(src, bs, 3 * D, dist);
    topk_kernel<<<(BB * NN) / 4, 256, 0, stream>>>(dist, idx);
    edge_fused_kernel<<<BB * Co, 256, 0, stream>>>(src, bs, D, Co, Wf[l],
                                                   Wd[l], idx, L[l].ooff,
                                                   xcat);
  }

  final_fused_kernel<<<dim3(NT, 6, BB), 256, 0, stream>>>(xcat, Wf[4], Wd[4],
                                                          part);
  final_reduce_kernel<<<(BB * 341 * 3 + 255) / 256, 256, 0, stream>>>(
      part, (float*)d_out);
}